// Round 9
// baseline (480.940 us; speedup 1.0000x reference)
//
#include <hip/hip_runtime.h>
#include <cstdint>
#include <cstddef>

typedef float f32x4 __attribute__((ext_vector_type(4)));
typedef __bf16 bf16x8_t __attribute__((ext_vector_type(8)));
typedef short s16x8_t __attribute__((ext_vector_type(8)));
typedef unsigned short u16x4_t __attribute__((ext_vector_type(4)));

#define NN 8192   // nodes
#define FD 512    // in features
#define HD 256    // hidden
#define CD 40     // classes

static __device__ __forceinline__ unsigned short f2bf(float f) {
    unsigned int u = __builtin_bit_cast(unsigned int, f);
    u += 0x7FFFu + ((u >> 16) & 1u);          // round-to-nearest-even
    return (unsigned short)(u >> 16);
}
static __device__ __forceinline__ float bf2f(unsigned short s) {
    unsigned int u = ((unsigned int)s) << 16;
    return __builtin_bit_cast(float, u);
}

typedef __attribute__((address_space(3))) unsigned int lds_u32_t;
typedef __attribute__((address_space(1))) const unsigned int gbl_u32_t;
static __device__ __forceinline__ void gload16(const void* g, const void* lds) {
    __builtin_amdgcn_global_load_lds((gbl_u32_t*)g, (lds_u32_t*)lds, 16, 0, 0);
}

// ---------------- K0: fused prep + xw1->B1T + ypack (heterogeneous grid) ----------------
// r7/r8 measured: heterogeneous overlap works — xw1 + ypack blocks hide inside prep's
// memory shadow (fused dispatch ~213us vs prep-alone 202us). Block roles:
// 0..511 xw1 (writes B1T rows 0..255 directly), 512..639 ypack (B1T rows 256..319),
// 640..8831 prep.
// prep notes (r1/r2 measured): NT loads + depth-1 SW pipeline, ~5.0 TB/s combined
// fabric = floor for 1.05 GB logical R+W. Per-row phase rotation REGRESSED — keep lockstep.
__global__ __launch_bounds__(256) void k_prep_xw1(
        const float* __restrict__ adj,
        const float* __restrict__ mask1,
        const float* __restrict__ mask2,     // may be null
        unsigned short* __restrict__ P1,
        unsigned short* __restrict__ P2,     // may be null
        float* __restrict__ sinv1,
        float* __restrict__ sinv2,           // may be null
        const float* __restrict__ x,
        const float* __restrict__ w1,
        const float* __restrict__ y,
        unsigned short* __restrict__ B1T) {
    __shared__ char smem[18432];             // aliased per block role
    const int t = threadIdx.x;

    if (blockIdx.x < 512) {
        // ---- xw1 body: B1T[n][k] rows 0..255 = (x @ w1)^T, bf16 ----
        float (*xs)[36] = (float(*)[36])smem;            // 64x36 f32 = 9216 B
        float (*ws)[68] = (float(*)[68])(smem + 9216);   // 32x68 f32 = 8704 B
        const int bid = blockIdx.x;
        const int m0 = (bid >> 2) * 64;      // k-range of B1T
        const int n0 = (bid & 3) * 64;       // n-range of B1T
        const int tx = t & 15, ty = t >> 4;
        float acc[4][4] = {};
        for (int k0 = 0; k0 < FD; k0 += 32) {
            for (int i = t; i < 512; i += 256) {
                int r = i >> 3, c = (i & 7) << 2;
                *(float4*)&xs[r][c] = *(const float4*)&x[(size_t)(m0 + r) * FD + k0 + c];
            }
            for (int i = t; i < 512; i += 256) {
                int r = i >> 4, c = (i & 15) << 2;
                *(float4*)&ws[r][c] = *(const float4*)&w1[(size_t)(k0 + r) * HD + n0 + c];
            }
            __syncthreads();
            for (int k = 0; k < 32; ++k) {
                float a_[4], b_[4];
                #pragma unroll
                for (int i = 0; i < 4; ++i) a_[i] = xs[ty * 4 + i][k];
                #pragma unroll
                for (int j = 0; j < 4; ++j) b_[j] = ws[k][tx * 4 + j];
                #pragma unroll
                for (int i = 0; i < 4; ++i)
                    #pragma unroll
                    for (int j = 0; j < 4; ++j) acc[i][j] += a_[i] * b_[j];
            }
            __syncthreads();
        }
        // transpose via LDS (reuse smem; xs/ws dead after last sync), then bf16 -> B1T
        float (*ot)[65] = (float(*)[65])smem;            // 64x65 f32 = 16640 B
        #pragma unroll
        for (int i = 0; i < 4; ++i)
            #pragma unroll
            for (int j = 0; j < 4; ++j)
                ot[tx * 4 + j][ty * 4 + i] = acc[i][j];  // ot[n_local][m_local]
        __syncthreads();
        #pragma unroll
        for (int u = 0; u < 2; ++u) {
            const int task = t + u * 256;                // 512 tasks
            const int nr = task >> 3, part = task & 7;
            unsigned short tmp[8];
            #pragma unroll
            for (int j = 0; j < 8; ++j) tmp[j] = f2bf(ot[nr][part * 8 + j]);
            *(s16x8_t*)&B1T[(size_t)(n0 + nr) * NN + m0 + part * 8] = *(s16x8_t*)tmp;
        }
        return;
    }

    if (blockIdx.x < 640) {
        // ---- ypack body: B1T rows 256..295 = y^T ; rows 296..319 = 0 ----
        float (*tl)[41] = (float(*)[41])smem;            // 64x41 f32 = 10496 B
        const int k0 = (blockIdx.x - 512) * 64;
        for (int u = 0; u < 10; ++u) {                   // 64x40 = 2560 floats, coalesced
            const int idx = t + u * 256;
            tl[idx / 40][idx % 40] = y[(size_t)k0 * CD + idx];
        }
        __syncthreads();
        for (int task = t; task < 320; task += 256) {    // 40 rows x 8 parts
            const int c = task >> 3, part = task & 7;
            unsigned short tmp[8];
            #pragma unroll
            for (int j = 0; j < 8; ++j) tmp[j] = f2bf(tl[part * 8 + j][c]);
            *(s16x8_t*)&B1T[(size_t)(256 + c) * NN + k0 + part * 8] = *(s16x8_t*)tmp;
        }
        for (int task = t; task < 192; task += 256) {    // 24 zero rows x 8 parts (GEMM1 pad)
            const int row = 296 + (task >> 3), part = task & 7;
            s16x8_t z = {};
            *(s16x8_t*)&B1T[(size_t)row * NN + k0 + part * 8] = z;
        }
        return;
    }

    // ---- prep body: P = bf16(adj .* mask), sinv = 1/max(rowsum|P|,eps) ----
    float* red1 = (float*)smem;              // 4 floats
    float* red2 = (float*)(smem + 16);       // 4 floats
    const int row = blockIdx.x - 640;
    const f32x4* __restrict__ ar  = (const f32x4*)(adj   + (size_t)row * NN);
    const f32x4* __restrict__ m1r = (const f32x4*)(mask1 + (size_t)row * NN);
    const f32x4* __restrict__ m2r = mask2 ? (const f32x4*)(mask2 + (size_t)row * NN) : nullptr;
    float s1 = 0.f, s2 = 0.f;

    f32x4 a  = __builtin_nontemporal_load(&ar[t]);
    f32x4 m1 = __builtin_nontemporal_load(&m1r[t]);
    f32x4 m2 = {};
    if (m2r) m2 = __builtin_nontemporal_load(&m2r[t]);

    #pragma unroll
    for (int j = 0; j < 8; ++j) {
        const int idx = j * 256 + t;
        f32x4 an = {}, m1n = {}, m2n = {};
        if (j < 7) {
            an  = __builtin_nontemporal_load(&ar[idx + 256]);
            m1n = __builtin_nontemporal_load(&m1r[idx + 256]);
            if (m2r) m2n = __builtin_nontemporal_load(&m2r[idx + 256]);
        }
        {
            const float p0 = a[0] * m1[0], p1 = a[1] * m1[1], p2 = a[2] * m1[2], p3 = a[3] * m1[3];
            s1 += fabsf(p0) + fabsf(p1) + fabsf(p2) + fabsf(p3);
            u16x4_t pk; pk.x = f2bf(p0); pk.y = f2bf(p1); pk.z = f2bf(p2); pk.w = f2bf(p3);
            *(u16x4_t*)&P1[(size_t)row * NN + idx * 4] = pk;
        }
        if (m2r) {
            const float p0 = a[0] * m2[0], p1 = a[1] * m2[1], p2 = a[2] * m2[2], p3 = a[3] * m2[3];
            s2 += fabsf(p0) + fabsf(p1) + fabsf(p2) + fabsf(p3);
            u16x4_t pk; pk.x = f2bf(p0); pk.y = f2bf(p1); pk.z = f2bf(p2); pk.w = f2bf(p3);
            *(u16x4_t*)&P2[(size_t)row * NN + idx * 4] = pk;
        }
        a = an; m1 = m1n; m2 = m2n;
    }
    #pragma unroll
    for (int d = 32; d; d >>= 1) { s1 += __shfl_xor(s1, d, 64); s2 += __shfl_xor(s2, d, 64); }
    if ((t & 63) == 0) { red1[t >> 6] = s1; red2[t >> 6] = s2; }
    __syncthreads();
    if (t == 0) {
        const float a1 = red1[0] + red1[1] + red1[2] + red1[3];
        sinv1[row] = 1.0f / fmaxf(a1, 1e-12f);
        if (sinv2) {
            const float a2 = red2[0] + red2[1] + red2[2] + red2[3];
            sinv2[row] = 1.0f / fmaxf(a2, 1e-12f);
        }
    }
}

// ---------------- K0b: standalone prep (second pass in !both mode) ----------------
__global__ __launch_bounds__(256) void k_prep(const float* __restrict__ adj,
                                              const float* __restrict__ mask1,
                                              const float* __restrict__ mask2,   // may be null
                                              unsigned short* __restrict__ P1,
                                              unsigned short* __restrict__ P2,   // may be null
                                              float* __restrict__ sinv1,
                                              float* __restrict__ sinv2) {       // may be null
    const int row = blockIdx.x;
    const int t = threadIdx.x;
    const f32x4* __restrict__ ar  = (const f32x4*)(adj   + (size_t)row * NN);
    const f32x4* __restrict__ m1r = (const f32x4*)(mask1 + (size_t)row * NN);
    const f32x4* __restrict__ m2r = mask2 ? (const f32x4*)(mask2 + (size_t)row * NN) : nullptr;
    float s1 = 0.f, s2 = 0.f;

    f32x4 a  = __builtin_nontemporal_load(&ar[t]);
    f32x4 m1 = __builtin_nontemporal_load(&m1r[t]);
    f32x4 m2 = {};
    if (m2r) m2 = __builtin_nontemporal_load(&m2r[t]);

    #pragma unroll
    for (int j = 0; j < 8; ++j) {
        const int idx = j * 256 + t;
        f32x4 an = {}, m1n = {}, m2n = {};
        if (j < 7) {
            an  = __builtin_nontemporal_load(&ar[idx + 256]);
            m1n = __builtin_nontemporal_load(&m1r[idx + 256]);
            if (m2r) m2n = __builtin_nontemporal_load(&m2r[idx + 256]);
        }
        {
            const float p0 = a[0] * m1[0], p1 = a[1] * m1[1], p2 = a[2] * m1[2], p3 = a[3] * m1[3];
            s1 += fabsf(p0) + fabsf(p1) + fabsf(p2) + fabsf(p3);
            u16x4_t pk; pk.x = f2bf(p0); pk.y = f2bf(p1); pk.z = f2bf(p2); pk.w = f2bf(p3);
            *(u16x4_t*)&P1[(size_t)row * NN + idx * 4] = pk;
        }
        if (m2r) {
            const float p0 = a[0] * m2[0], p1 = a[1] * m2[1], p2 = a[2] * m2[2], p3 = a[3] * m2[3];
            s2 += fabsf(p0) + fabsf(p1) + fabsf(p2) + fabsf(p3);
            u16x4_t pk; pk.x = f2bf(p0); pk.y = f2bf(p1); pk.z = f2bf(p2); pk.w = f2bf(p3);
            *(u16x4_t*)&P2[(size_t)row * NN + idx * 4] = pk;
        }
        a = an; m1 = m1n; m2 = m2n;
    }
    __shared__ float red1[4], red2[4];
    #pragma unroll
    for (int d = 32; d; d >>= 1) { s1 += __shfl_xor(s1, d, 64); s2 += __shfl_xor(s2, d, 64); }
    if ((t & 63) == 0) { red1[t >> 6] = s1; red2[t >> 6] = s2; }
    __syncthreads();
    if (t == 0) {
        const float a1 = red1[0] + red1[1] + red1[2] + red1[3];
        sinv1[row] = 1.0f / fmaxf(a1, 1e-12f);
        if (sinv2) {
            const float a2 = red2[0] + red2[1] + red2[2] + red2[3];
            sinv2[row] = 1.0f / fmaxf(a2, 1e-12f);
        }
    }
}

// ---------------- K3: m97-style GEMM: Cp[ks] = A[BM-tile] @ Bt^T (both row-major in K) ----------------
// BM=128, BK=64. XOR chunk-swizzle applied on the global source and on the ds_read (both-sides).
// For NTILES>1: XCD-grouping block remap (r3, measured win) so A-panel siblings share L2.
// B-stage loop is generic in BN (BN/8 x 1KB wave-insts) so non-multiple-of-128 BN works.
template<int BN, int WM, int WN, int SPLIT, int NTILES>
__global__ __launch_bounds__(256) void k_gemm(const unsigned short* __restrict__ A,
                                              const unsigned short* __restrict__ Bt,
                                              float* __restrict__ Cp) {
    constexpr int BM = 128, BK = 64;
    constexpr int MF = BM / (WM * 16);
    constexpr int NF = BN / (WN * 16);
    constexpr int NSTR = NTILES * BN;     // Cp row stride
    constexpr int MT = NN / BM;           // 64 m-tiles
    __shared__ unsigned short As[BM * BK];
    __shared__ unsigned short Bs[BN * BK];
    int mt, ks, nt;
    if constexpr (NTILES > 1) {
        constexpr int NXCD = 8;
        constexpr int PAIRS = MT * SPLIT;              // (mt,ks) pairs
        static_assert(PAIRS % NXCD == 0, "pair count must split across XCDs");
        constexpr int PPX = PAIRS / NXCD;              // pairs per XCD
        const int L = blockIdx.x;
        const int x = L % NXCD, q = L / NXCD;          // XCD id, slot on that XCD
        const int pr = x * PPX + q / NTILES;           // pair index
        nt = q % NTILES;
        mt = pr / SPLIT;
        ks = pr % SPLIT;
    } else {
        int b = blockIdx.x;
        nt = 0;
        ks = b % SPLIT;  b /= SPLIT;
        mt = b;
    }
    const int m0 = mt * BM, n0 = nt * BN;
    const int t = threadIdx.x, w = t >> 6, ln = t & 63;
    const int wn = w % WN, wm = w / WN;
    const int lrow = ln & 15, lkq = ln >> 4;
    const int kbeg = ks * (NN / SPLIT), kend = kbeg + (NN / SPLIT);

    f32x4 acc[MF][NF] = {};
    for (int kb = kbeg; kb < kend; kb += BK) {
        // stage A (16KB): 16 wave-insts of 1KB; lane l -> LDS base + l*16
        #pragma unroll
        for (int i = 0; i < 4; ++i) {
            const int off = (w * 4 + i) * 1024 + ln * 16;
            const int r = off >> 7, ch = (off >> 4) & 7;
            gload16(A + (size_t)(m0 + r) * NN + kb + ((ch ^ (r & 7)) << 3),
                    &As[(w * 4 + i) * 512]);
        }
        // stage B (BN*128 bytes = BN/8 x 1KB insts, round-robin over waves)
        #pragma unroll
        for (int i = w; i < (BN >> 3); i += 4) {
            const int off = i * 1024 + ln * 16;
            const int r = off >> 7, ch = (off >> 4) & 7;
            gload16(Bt + (size_t)(n0 + r) * NN + kb + ((ch ^ (r & 7)) << 3),
                    &Bs[i * 512]);
        }
        __syncthreads();   // compiler drains vmcnt before barrier

        bf16x8_t af[MF][2];
        #pragma unroll
        for (int mf = 0; mf < MF; ++mf)
            #pragma unroll
            for (int kh = 0; kh < 2; ++kh) {
                const int r = wm * (MF * 16) + mf * 16 + lrow;
                const int ch = (kh * 4 + lkq) ^ (r & 7);
                af[mf][kh] = __builtin_bit_cast(bf16x8_t, *(const s16x8_t*)&As[r * 64 + ch * 8]);
            }
        bf16x8_t bfr[NF][2];
        #pragma unroll
        for (int nf = 0; nf < NF; ++nf)
            #pragma unroll
            for (int kh = 0; kh < 2; ++kh) {
                const int r = wn * (NF * 16) + nf * 16 + lrow;
                const int ch = (kh * 4 + lkq) ^ (r & 7);
                bfr[nf][kh] = __builtin_bit_cast(bf16x8_t, *(const s16x8_t*)&Bs[r * 64 + ch * 8]);
            }
        #pragma unroll
        for (int kh = 0; kh < 2; ++kh)
            #pragma unroll
            for (int mf = 0; mf < MF; ++mf)
                #pragma unroll
                for (int nf = 0; nf < NF; ++nf)
                    acc[mf][nf] = __builtin_amdgcn_mfma_f32_16x16x32_bf16(
                        af[mf][kh], bfr[nf][kh], acc[mf][nf], 0, 0, 0);
        __syncthreads();
    }
    // epilogue: partial f32 store. C/D layout: col = lane&15 (from Bt row), row = (lane>>4)*4+e (from A row)
    #pragma unroll
    for (int mf = 0; mf < MF; ++mf)
        #pragma unroll
        for (int nf = 0; nf < NF; ++nf)
            #pragma unroll
            for (int e = 0; e < 4; ++e) {
                const int m = m0 + wm * (MF * 16) + mf * 16 + lkq * 4 + e;
                const int n = n0 + wn * (NF * 16) + nf * 16 + lrow;
                Cp[((size_t)ks * NN + m) * NSTR + n] = acc[mf][nf][e];
            }
}

// ---------------- K4: fused finC + hw2 ----------------
// finC block b produces h1 rows b*32..b*32+31; hw2 block b consumes exactly those rows.
// h1 lives only in LDS. hw2 inner loop r8-restructured: f32x4 w2 reads (wave-broadcast,
// conflict-free) + bf16x8 h reads — same k-summation order, bit-identical results,
// ~2x fewer LDS cycles than the old 5x scalar-b32 form.
// B2T zero rows 80..95 no longer written (GEMM2 is BN=80 and never reads them).
__global__ __launch_bounds__(256) void k_finC2(const float* __restrict__ U,   // [2][NN][320]
                                               const float* __restrict__ sinv1,
                                               const float* __restrict__ b1,
                                               const float* __restrict__ w2,
                                               unsigned short* __restrict__ B2T) {
    __shared__ float w2s[HD * CD];                 // 40 KB
    __shared__ unsigned short h1s[32][264];        // 16.9 KB
    __shared__ float otp[CD][33];                  // 5.3 KB
    const int t = threadIdx.x;
    const int mb = blockIdx.x * 32;

    for (int i = t; i < HD * CD; i += 256) w2s[i] = w2[i];

    // ---- finC phase: U1 = sum(2 parts)*sinv1; h -> LDS bf16; yh1 -> B2T rows 40..79 ----
    {
        const int r = t >> 3, l8 = t & 7;
        const int m = mb + r;
        const float si = sinv1[m];
        const float* __restrict__ u0 = U + (size_t)m * 320;
        const float* __restrict__ u1 = U + (size_t)(NN + m) * 320;
        #pragma unroll
        for (int i = 0; i < 10; ++i) {
            const int c = (l8 + i * 8) * 4;       // 0..316
            f32x4 a = *(const f32x4*)&u0[c];
            f32x4 b = *(const f32x4*)&u1[c];
            f32x4 v;
            #pragma unroll
            for (int e = 0; e < 4; ++e) v[e] = (a[e] + b[e]) * si;
            if (i < 8) {                           // c < 256: hidden part -> LDS
                u16x4_t pk;
                #pragma unroll
                for (int e = 0; e < 4; ++e) {
                    const float hv = fmaxf(v[e] + b1[c + e], 0.f);
                    ((unsigned short*)&pk)[e] = f2bf(hv);
                }
                *(u16x4_t*)&h1s[r][c] = pk;
            } else {                               // c in 256..316: y_hat part
                #pragma unroll
                for (int e = 0; e < 4; ++e) {
                    const int cc = c + e;
                    if (cc < 296) B2T[(size_t)(40 + cc - 256) * NN + m] = f2bf(v[e]);
                }
            }
        }
    }
    __syncthreads();

    // ---- hw2 phase: support2 = h1 @ w2 -> B2T rows 0..39 ----
    // 320 tasks: task -> m = task&31 (h-row), g = task>>5 (4-col group of w2).
    for (int task = t; task < 320; task += 256) {
        const int m = task & 31, g = task >> 5;
        f32x4 a4 = {};
        for (int k8 = 0; k8 < 32; ++k8) {
            const s16x8_t h8 = *(const s16x8_t*)&h1s[m][k8 * 8];
            #pragma unroll
            for (int e = 0; e < 8; ++e) {
                const float hv = bf2f((unsigned short)h8[e]);
                const f32x4 w4 = *(const f32x4*)&w2s[(k8 * 8 + e) * CD + g * 4];
                a4 += hv * w4;
            }
        }
        #pragma unroll
        for (int e = 0; e < 4; ++e) otp[g * 4 + e][m] = a4[e];
    }
    __syncthreads();
    for (int i = t; i < CD * 32; i += 256) {
        const int n = i >> 5, mm = i & 31;
        B2T[(size_t)n * NN + mb + mm] = f2bf(otp[n][mm]);
    }
}

// ---------------- K6: finD — sum 8 partials (80-wide), *sinv2, +b2, log_softmax both, store ----------------
__global__ __launch_bounds__(256) void k_finD(const float* __restrict__ U,   // [8][NN][80]
                                              const float* __restrict__ sinv2,
                                              const float* __restrict__ b2,
                                              float* __restrict__ out) {
    __shared__ float vt[32][84];
    const int t = threadIdx.x;
    const int mb = blockIdx.x * 32;
    for (int i = t; i < 32 * 20; i += 256) {
        const int r = i / 20, f4 = i % 20;
        const int m = mb + r;
        f32x4 s = {};
        #pragma unroll
        for (int p = 0; p < 8; ++p) {
            f32x4 v = *(const f32x4*)&U[((size_t)p * NN + m) * 80 + f4 * 4];
            #pragma unroll
            for (int e = 0; e < 4; ++e) s[e] += v[e];
        }
        const float si = sinv2[m];
        #pragma unroll
        for (int e = 0; e < 4; ++e) {
            const int c = f4 * 4 + e;
            float v = s[e] * si;
            if (c < CD) v += b2[c];
            vt[r][c] = v;
        }
    }
    __syncthreads();
    const int l8 = t & 7;
    #pragma unroll
    for (int pass = 0; pass < 2; ++pass) {
        const int task = pass * 32 + (t >> 3);
        const int row = task & 31, mat = task >> 5;
        float vals[5];
        float mx = -3.0e38f;
        #pragma unroll
        for (int j = 0; j < 5; ++j) { vals[j] = vt[row][mat * CD + l8 + 8 * j]; mx = fmaxf(mx, vals[j]); }
        mx = fmaxf(mx, __shfl_xor(mx, 4, 8));
        mx = fmaxf(mx, __shfl_xor(mx, 2, 8));
        mx = fmaxf(mx, __shfl_xor(mx, 1, 8));
        float se = 0.f;
        #pragma unroll
        for (int j = 0; j < 5; ++j) se += expf(vals[j] - mx);
        se += __shfl_xor(se, 4, 8);
        se += __shfl_xor(se, 2, 8);
        se += __shfl_xor(se, 1, 8);
        const float ls = logf(se);
        float* op = out + (size_t)mat * (NN * CD) + (size_t)(mb + row) * CD;
        #pragma unroll
        for (int j = 0; j < 5; ++j) op[l8 + 8 * j] = vals[j] - mx - ls;
    }
}

extern "C" void kernel_launch(void* const* d_in, const int* in_sizes, int n_in,
                              void* d_out, int out_size, void* d_ws, size_t ws_size,
                              hipStream_t stream) {
    (void)in_sizes; (void)n_in; (void)out_size;
    const float* x     = (const float*)d_in[0];
    const float* adj   = (const float*)d_in[1];
    const float* y     = (const float*)d_in[2];
    const float* mask1 = (const float*)d_in[3];
    const float* mask2 = (const float*)d_in[4];
    const float* w1    = (const float*)d_in[5];
    const float* b1    = (const float*)d_in[6];
    const float* w2    = (const float*)d_in[7];
    const float* b2    = (const float*)d_in[8];
    float* out = (float*)d_out;

    const bool both = ws_size >= 313065472ULL;   // P1+P2 resident simultaneously
    char* p = (char*)d_ws;
    unsigned short* P1 = (unsigned short*)p; p += 134217728;
    unsigned short* P2 = P1;
    if (both) { P2 = (unsigned short*)p; p += 134217728; }
    unsigned short* B1T  = (unsigned short*)p; p += 5242880;    // 320x8192 bf16
    unsigned short* B2T  = (unsigned short*)p; p += 1572864;    // 96x8192 bf16 (80 rows used)
    float*          U    = (float*)p;          p += 20971520;   // overlay: Uc[2][8192][320] / Ud[8][8192][80]
    float*          sinv1 = (float*)p;         p += 32768;
    float*          sinv2 = (float*)p;         p += 32768;

    if (both) {
        hipLaunchKernelGGL(k_prep_xw1, dim3(8832), dim3(256), 0, stream,
                           adj, mask1, mask2, P1, P2, sinv1, sinv2, x, w1, y, B1T);
    } else {
        hipLaunchKernelGGL(k_prep_xw1, dim3(8832), dim3(256), 0, stream,
                           adj, mask1, (const float*)nullptr, P1, (unsigned short*)nullptr,
                           sinv1, (float*)nullptr, x, w1, y, B1T);
    }
    hipLaunchKernelGGL(HIP_KERNEL_NAME(k_gemm<64, 2, 2, 2, 5>), dim3(640), dim3(256), 0, stream,
                       P1, B1T, U);
    hipLaunchKernelGGL(k_finC2,   dim3(256),  dim3(256), 0, stream, U, sinv1, b1, w2, B2T);
    if (!both) {
        hipLaunchKernelGGL(k_prep, dim3(8192), dim3(256), 0, stream,
                           adj, mask2, (const float*)nullptr, P1, (unsigned short*)nullptr,
                           sinv2, (float*)nullptr);
    }
    hipLaunchKernelGGL(HIP_KERNEL_NAME(k_gemm<80, 4, 1, 8, 1>), dim3(512), dim3(256), 0, stream,
                       P2, B2T, U);
    hipLaunchKernelGGL(k_finD,    dim3(256),  dim3(256), 0, stream, U, sinv2, b2, out);
}

// Round 10
// 336.075 us; speedup vs baseline: 1.4311x; 1.4311x over previous
//
#include <hip/hip_runtime.h>
#include <cstdint>
#include <cstddef>

typedef float f32x4 __attribute__((ext_vector_type(4)));
typedef __bf16 bf16x8_t __attribute__((ext_vector_type(8)));
typedef short s16x8_t __attribute__((ext_vector_type(8)));
typedef unsigned short u16x4_t __attribute__((ext_vector_type(4)));

#define NN 8192   // nodes
#define FD 512    // in features
#define HD 256    // hidden
#define CD 40     // classes

static __device__ __forceinline__ unsigned short f2bf(float f) {
    unsigned int u = __builtin_bit_cast(unsigned int, f);
    u += 0x7FFFu + ((u >> 16) & 1u);          // round-to-nearest-even
    return (unsigned short)(u >> 16);
}
static __device__ __forceinline__ float bf2f(unsigned short s) {
    unsigned int u = ((unsigned int)s) << 16;
    return __builtin_bit_cast(float, u);
}

typedef __attribute__((address_space(3))) unsigned int lds_u32_t;
typedef __attribute__((address_space(1))) const unsigned int gbl_u32_t;
static __device__ __forceinline__ void gload16(const void* g, const void* lds) {
    __builtin_amdgcn_global_load_lds((gbl_u32_t*)g, (lds_u32_t*)lds, 16, 0, 0);
}

// ---------------- K0: fused prep + xw1->B1T + ypack (heterogeneous grid) ----------------
// r7/r8 measured: heterogeneous overlap works — xw1 + ypack blocks hide inside prep's
// memory shadow (fused dispatch ~213us vs prep-alone 202us). Block roles:
// 0..511 xw1 (writes B1T rows 0..255 directly), 512..639 ypack (B1T rows 256..319),
// 640..8831 prep.
// prep notes (r1/r2 measured): NT loads + depth-1 SW pipeline, ~5.0 TB/s combined
// fabric = floor for 1.05 GB logical R+W. Per-row phase rotation REGRESSED — keep lockstep.
// r9 lesson: NEVER bundle changes; runtime-start unrolled loops around gload16 regressed
// the tail 2x. B-stage loops must be static-index + wave-uniform guard.
__global__ __launch_bounds__(256) void k_prep_xw1(
        const float* __restrict__ adj,
        const float* __restrict__ mask1,
        const float* __restrict__ mask2,     // may be null
        unsigned short* __restrict__ P1,
        unsigned short* __restrict__ P2,     // may be null
        float* __restrict__ sinv1,
        float* __restrict__ sinv2,           // may be null
        const float* __restrict__ x,
        const float* __restrict__ w1,
        const float* __restrict__ y,
        unsigned short* __restrict__ B1T) {
    __shared__ char smem[18432];             // aliased per block role
    const int t = threadIdx.x;

    if (blockIdx.x < 512) {
        // ---- xw1 body: B1T[n][k] rows 0..255 = (x @ w1)^T, bf16 ----
        float (*xs)[36] = (float(*)[36])smem;            // 64x36 f32 = 9216 B
        float (*ws)[68] = (float(*)[68])(smem + 9216);   // 32x68 f32 = 8704 B
        const int bid = blockIdx.x;
        const int m0 = (bid >> 2) * 64;      // k-range of B1T
        const int n0 = (bid & 3) * 64;       // n-range of B1T
        const int tx = t & 15, ty = t >> 4;
        float acc[4][4] = {};
        for (int k0 = 0; k0 < FD; k0 += 32) {
            for (int i = t; i < 512; i += 256) {
                int r = i >> 3, c = (i & 7) << 2;
                *(float4*)&xs[r][c] = *(const float4*)&x[(size_t)(m0 + r) * FD + k0 + c];
            }
            for (int i = t; i < 512; i += 256) {
                int r = i >> 4, c = (i & 15) << 2;
                *(float4*)&ws[r][c] = *(const float4*)&w1[(size_t)(k0 + r) * HD + n0 + c];
            }
            __syncthreads();
            for (int k = 0; k < 32; ++k) {
                float a_[4], b_[4];
                #pragma unroll
                for (int i = 0; i < 4; ++i) a_[i] = xs[ty * 4 + i][k];
                #pragma unroll
                for (int j = 0; j < 4; ++j) b_[j] = ws[k][tx * 4 + j];
                #pragma unroll
                for (int i = 0; i < 4; ++i)
                    #pragma unroll
                    for (int j = 0; j < 4; ++j) acc[i][j] += a_[i] * b_[j];
            }
            __syncthreads();
        }
        // transpose via LDS (reuse smem; xs/ws dead after last sync), then bf16 -> B1T
        float (*ot)[65] = (float(*)[65])smem;            // 64x65 f32 = 16640 B
        #pragma unroll
        for (int i = 0; i < 4; ++i)
            #pragma unroll
            for (int j = 0; j < 4; ++j)
                ot[tx * 4 + j][ty * 4 + i] = acc[i][j];  // ot[n_local][m_local]
        __syncthreads();
        #pragma unroll
        for (int u = 0; u < 2; ++u) {
            const int task = t + u * 256;                // 512 tasks
            const int nr = task >> 3, part = task & 7;
            unsigned short tmp[8];
            #pragma unroll
            for (int j = 0; j < 8; ++j) tmp[j] = f2bf(ot[nr][part * 8 + j]);
            *(s16x8_t*)&B1T[(size_t)(n0 + nr) * NN + m0 + part * 8] = *(s16x8_t*)tmp;
        }
        return;
    }

    if (blockIdx.x < 640) {
        // ---- ypack body: B1T rows 256..295 = y^T ; rows 296..319 = 0 ----
        float (*tl)[41] = (float(*)[41])smem;            // 64x41 f32 = 10496 B
        const int k0 = (blockIdx.x - 512) * 64;
        for (int u = 0; u < 10; ++u) {                   // 64x40 = 2560 floats, coalesced
            const int idx = t + u * 256;
            tl[idx / 40][idx % 40] = y[(size_t)k0 * CD + idx];
        }
        __syncthreads();
        for (int task = t; task < 320; task += 256) {    // 40 rows x 8 parts
            const int c = task >> 3, part = task & 7;
            unsigned short tmp[8];
            #pragma unroll
            for (int j = 0; j < 8; ++j) tmp[j] = f2bf(tl[part * 8 + j][c]);
            *(s16x8_t*)&B1T[(size_t)(256 + c) * NN + k0 + part * 8] = *(s16x8_t*)tmp;
        }
        for (int task = t; task < 192; task += 256) {    // 24 zero rows x 8 parts (GEMM1 pad)
            const int row = 296 + (task >> 3), part = task & 7;
            s16x8_t z = {};
            *(s16x8_t*)&B1T[(size_t)row * NN + k0 + part * 8] = z;
        }
        return;
    }

    // ---- prep body: P = bf16(adj .* mask), sinv = 1/max(rowsum|P|,eps) ----
    float* red1 = (float*)smem;              // 4 floats
    float* red2 = (float*)(smem + 16);       // 4 floats
    const int row = blockIdx.x - 640;
    const f32x4* __restrict__ ar  = (const f32x4*)(adj   + (size_t)row * NN);
    const f32x4* __restrict__ m1r = (const f32x4*)(mask1 + (size_t)row * NN);
    const f32x4* __restrict__ m2r = mask2 ? (const f32x4*)(mask2 + (size_t)row * NN) : nullptr;
    float s1 = 0.f, s2 = 0.f;

    f32x4 a  = __builtin_nontemporal_load(&ar[t]);
    f32x4 m1 = __builtin_nontemporal_load(&m1r[t]);
    f32x4 m2 = {};
    if (m2r) m2 = __builtin_nontemporal_load(&m2r[t]);

    #pragma unroll
    for (int j = 0; j < 8; ++j) {
        const int idx = j * 256 + t;
        f32x4 an = {}, m1n = {}, m2n = {};
        if (j < 7) {
            an  = __builtin_nontemporal_load(&ar[idx + 256]);
            m1n = __builtin_nontemporal_load(&m1r[idx + 256]);
            if (m2r) m2n = __builtin_nontemporal_load(&m2r[idx + 256]);
        }
        {
            const float p0 = a[0] * m1[0], p1 = a[1] * m1[1], p2 = a[2] * m1[2], p3 = a[3] * m1[3];
            s1 += fabsf(p0) + fabsf(p1) + fabsf(p2) + fabsf(p3);
            u16x4_t pk; pk.x = f2bf(p0); pk.y = f2bf(p1); pk.z = f2bf(p2); pk.w = f2bf(p3);
            *(u16x4_t*)&P1[(size_t)row * NN + idx * 4] = pk;
        }
        if (m2r) {
            const float p0 = a[0] * m2[0], p1 = a[1] * m2[1], p2 = a[2] * m2[2], p3 = a[3] * m2[3];
            s2 += fabsf(p0) + fabsf(p1) + fabsf(p2) + fabsf(p3);
            u16x4_t pk; pk.x = f2bf(p0); pk.y = f2bf(p1); pk.z = f2bf(p2); pk.w = f2bf(p3);
            *(u16x4_t*)&P2[(size_t)row * NN + idx * 4] = pk;
        }
        a = an; m1 = m1n; m2 = m2n;
    }
    #pragma unroll
    for (int d = 32; d; d >>= 1) { s1 += __shfl_xor(s1, d, 64); s2 += __shfl_xor(s2, d, 64); }
    if ((t & 63) == 0) { red1[t >> 6] = s1; red2[t >> 6] = s2; }
    __syncthreads();
    if (t == 0) {
        const float a1 = red1[0] + red1[1] + red1[2] + red1[3];
        sinv1[row] = 1.0f / fmaxf(a1, 1e-12f);
        if (sinv2) {
            const float a2 = red2[0] + red2[1] + red2[2] + red2[3];
            sinv2[row] = 1.0f / fmaxf(a2, 1e-12f);
        }
    }
}

// ---------------- K0b: standalone prep (second pass in !both mode) ----------------
__global__ __launch_bounds__(256) void k_prep(const float* __restrict__ adj,
                                              const float* __restrict__ mask1,
                                              const float* __restrict__ mask2,   // may be null
                                              unsigned short* __restrict__ P1,
                                              unsigned short* __restrict__ P2,   // may be null
                                              float* __restrict__ sinv1,
                                              float* __restrict__ sinv2) {       // may be null
    const int row = blockIdx.x;
    const int t = threadIdx.x;
    const f32x4* __restrict__ ar  = (const f32x4*)(adj   + (size_t)row * NN);
    const f32x4* __restrict__ m1r = (const f32x4*)(mask1 + (size_t)row * NN);
    const f32x4* __restrict__ m2r = mask2 ? (const f32x4*)(mask2 + (size_t)row * NN) : nullptr;
    float s1 = 0.f, s2 = 0.f;

    f32x4 a  = __builtin_nontemporal_load(&ar[t]);
    f32x4 m1 = __builtin_nontemporal_load(&m1r[t]);
    f32x4 m2 = {};
    if (m2r) m2 = __builtin_nontemporal_load(&m2r[t]);

    #pragma unroll
    for (int j = 0; j < 8; ++j) {
        const int idx = j * 256 + t;
        f32x4 an = {}, m1n = {}, m2n = {};
        if (j < 7) {
            an  = __builtin_nontemporal_load(&ar[idx + 256]);
            m1n = __builtin_nontemporal_load(&m1r[idx + 256]);
            if (m2r) m2n = __builtin_nontemporal_load(&m2r[idx + 256]);
        }
        {
            const float p0 = a[0] * m1[0], p1 = a[1] * m1[1], p2 = a[2] * m1[2], p3 = a[3] * m1[3];
            s1 += fabsf(p0) + fabsf(p1) + fabsf(p2) + fabsf(p3);
            u16x4_t pk; pk.x = f2bf(p0); pk.y = f2bf(p1); pk.z = f2bf(p2); pk.w = f2bf(p3);
            *(u16x4_t*)&P1[(size_t)row * NN + idx * 4] = pk;
        }
        if (m2r) {
            const float p0 = a[0] * m2[0], p1 = a[1] * m2[1], p2 = a[2] * m2[2], p3 = a[3] * m2[3];
            s2 += fabsf(p0) + fabsf(p1) + fabsf(p2) + fabsf(p3);
            u16x4_t pk; pk.x = f2bf(p0); pk.y = f2bf(p1); pk.z = f2bf(p2); pk.w = f2bf(p3);
            *(u16x4_t*)&P2[(size_t)row * NN + idx * 4] = pk;
        }
        a = an; m1 = m1n; m2 = m2n;
    }
    __shared__ float red1[4], red2[4];
    #pragma unroll
    for (int d = 32; d; d >>= 1) { s1 += __shfl_xor(s1, d, 64); s2 += __shfl_xor(s2, d, 64); }
    if ((t & 63) == 0) { red1[t >> 6] = s1; red2[t >> 6] = s2; }
    __syncthreads();
    if (t == 0) {
        const float a1 = red1[0] + red1[1] + red1[2] + red1[3];
        sinv1[row] = 1.0f / fmaxf(a1, 1e-12f);
        if (sinv2) {
            const float a2 = red2[0] + red2[1] + red2[2] + red2[3];
            sinv2[row] = 1.0f / fmaxf(a2, 1e-12f);
        }
    }
}

// ---------------- K3: m97-style GEMM: Cp[ks] = A[BM-tile] @ Bt^T (both row-major in K) ----------------
// BM=128, BK=64. XOR chunk-swizzle applied on the global source and on the ds_read (both-sides).
// For NTILES>1: XCD-grouping block remap (r3, measured win) so A-panel siblings share L2.
// B-stage: STATIC index ci = w*NBIC + i with wave-uniform guard (ci < CH). For BN=64/96 the
// guard folds away -> codegen identical to the verified r8 kernel. (r9's runtime-start loop
// variant regressed the tail 2x — do not reintroduce.)
template<int BN, int WM, int WN, int SPLIT, int NTILES>
__global__ __launch_bounds__(256) void k_gemm(const unsigned short* __restrict__ A,
                                              const unsigned short* __restrict__ Bt,
                                              float* __restrict__ Cp) {
    constexpr int BM = 128, BK = 64;
    constexpr int MF = BM / (WM * 16);
    constexpr int NF = BN / (WN * 16);
    constexpr int CH = BN >> 3;           // 1KB B chunks
    constexpr int NBIC = (CH + 3) >> 2;   // chunks per wave (ceil)
    constexpr int NSTR = NTILES * BN;     // Cp row stride
    constexpr int MT = NN / BM;           // 64 m-tiles
    __shared__ unsigned short As[BM * BK];
    __shared__ unsigned short Bs[BN * BK];
    int mt, ks, nt;
    if constexpr (NTILES > 1) {
        constexpr int NXCD = 8;
        constexpr int PAIRS = MT * SPLIT;              // (mt,ks) pairs
        static_assert(PAIRS % NXCD == 0, "pair count must split across XCDs");
        constexpr int PPX = PAIRS / NXCD;              // pairs per XCD
        const int L = blockIdx.x;
        const int x = L % NXCD, q = L / NXCD;          // XCD id, slot on that XCD
        const int pr = x * PPX + q / NTILES;           // pair index
        nt = q % NTILES;
        mt = pr / SPLIT;
        ks = pr % SPLIT;
    } else {
        int b = blockIdx.x;
        nt = 0;
        ks = b % SPLIT;  b /= SPLIT;
        mt = b;
    }
    const int m0 = mt * BM, n0 = nt * BN;
    const int t = threadIdx.x, w = t >> 6, ln = t & 63;
    const int wn = w % WN, wm = w / WN;
    const int lrow = ln & 15, lkq = ln >> 4;
    const int kbeg = ks * (NN / SPLIT), kend = kbeg + (NN / SPLIT);

    f32x4 acc[MF][NF] = {};
    for (int kb = kbeg; kb < kend; kb += BK) {
        // stage A (16KB): 16 wave-insts of 1KB; lane l -> LDS base + l*16
        #pragma unroll
        for (int i = 0; i < 4; ++i) {
            const int off = (w * 4 + i) * 1024 + ln * 16;
            const int r = off >> 7, ch = (off >> 4) & 7;
            gload16(A + (size_t)(m0 + r) * NN + kb + ((ch ^ (r & 7)) << 3),
                    &As[(w * 4 + i) * 512]);
        }
        // stage B (CH x 1KB insts; static per-wave chunks, wave-uniform guard)
        #pragma unroll
        for (int i = 0; i < NBIC; ++i) {
            const int ci = w * NBIC + i;
            if (ci < CH) {
                const int off = ci * 1024 + ln * 16;
                const int r = off >> 7, ch = (off >> 4) & 7;
                gload16(Bt + (size_t)(n0 + r) * NN + kb + ((ch ^ (r & 7)) << 3),
                        &Bs[ci * 512]);
            }
        }
        __syncthreads();   // compiler drains vmcnt before barrier

        bf16x8_t af[MF][2];
        #pragma unroll
        for (int mf = 0; mf < MF; ++mf)
            #pragma unroll
            for (int kh = 0; kh < 2; ++kh) {
                const int r = wm * (MF * 16) + mf * 16 + lrow;
                const int ch = (kh * 4 + lkq) ^ (r & 7);
                af[mf][kh] = __builtin_bit_cast(bf16x8_t, *(const s16x8_t*)&As[r * 64 + ch * 8]);
            }
        bf16x8_t bfr[NF][2];
        #pragma unroll
        for (int nf = 0; nf < NF; ++nf)
            #pragma unroll
            for (int kh = 0; kh < 2; ++kh) {
                const int r = wn * (NF * 16) + nf * 16 + lrow;
                const int ch = (kh * 4 + lkq) ^ (r & 7);
                bfr[nf][kh] = __builtin_bit_cast(bf16x8_t, *(const s16x8_t*)&Bs[r * 64 + ch * 8]);
            }
        #pragma unroll
        for (int kh = 0; kh < 2; ++kh)
            #pragma unroll
            for (int mf = 0; mf < MF; ++mf)
                #pragma unroll
                for (int nf = 0; nf < NF; ++nf)
                    acc[mf][nf] = __builtin_amdgcn_mfma_f32_16x16x32_bf16(
                        af[mf][kh], bfr[nf][kh], acc[mf][nf], 0, 0, 0);
        __syncthreads();
    }
    // epilogue: partial f32 store. C/D layout: col = lane&15 (from Bt row), row = (lane>>4)*4+e (from A row)
    #pragma unroll
    for (int mf = 0; mf < MF; ++mf)
        #pragma unroll
        for (int nf = 0; nf < NF; ++nf)
            #pragma unroll
            for (int e = 0; e < 4; ++e) {
                const int m = m0 + wm * (MF * 16) + mf * 16 + lkq * 4 + e;
                const int n = n0 + wn * (NF * 16) + nf * 16 + lrow;
                Cp[((size_t)ks * NN + m) * NSTR + n] = acc[mf][nf][e];
            }
}

// ---------------- K4: fused finC + hw2 (r8-verified form) ----------------
// finC block b produces h1 rows b*32..b*32+31; hw2 block b consumes exactly those rows.
// h1 lives only in LDS. B2T zero rows 80..95 no longer written (GEMM2 is BN=80).
__global__ __launch_bounds__(256) void k_finC2(const float* __restrict__ U,   // [2][NN][320]
                                               const float* __restrict__ sinv1,
                                               const float* __restrict__ b1,
                                               const float* __restrict__ w2,
                                               unsigned short* __restrict__ B2T) {
    __shared__ float w2s[HD * CD];                 // 40 KB
    __shared__ unsigned short h1s[32][264];        // 16.9 KB
    __shared__ float otp[CD][33];                  // 5.3 KB
    const int t = threadIdx.x;
    const int mb = blockIdx.x * 32;

    for (int i = t; i < HD * CD; i += 256) w2s[i] = w2[i];

    // ---- finC phase: U1 = sum(2 parts)*sinv1; h -> LDS bf16; yh1 -> B2T rows 40..79 ----
    {
        const int r = t >> 3, l8 = t & 7;
        const int m = mb + r;
        const float si = sinv1[m];
        const float* __restrict__ u0 = U + (size_t)m * 320;
        const float* __restrict__ u1 = U + (size_t)(NN + m) * 320;
        #pragma unroll
        for (int i = 0; i < 10; ++i) {
            const int c = (l8 + i * 8) * 4;       // 0..316
            f32x4 a = *(const f32x4*)&u0[c];
            f32x4 b = *(const f32x4*)&u1[c];
            f32x4 v;
            #pragma unroll
            for (int e = 0; e < 4; ++e) v[e] = (a[e] + b[e]) * si;
            if (i < 8) {                           // c < 256: hidden part -> LDS
                u16x4_t pk;
                #pragma unroll
                for (int e = 0; e < 4; ++e) {
                    const float hv = fmaxf(v[e] + b1[c + e], 0.f);
                    ((unsigned short*)&pk)[e] = f2bf(hv);
                }
                *(u16x4_t*)&h1s[r][c] = pk;
            } else {                               // c in 256..316: y_hat part
                #pragma unroll
                for (int e = 0; e < 4; ++e) {
                    const int cc = c + e;
                    if (cc < 296) B2T[(size_t)(40 + cc - 256) * NN + m] = f2bf(v[e]);
                }
            }
        }
    }
    __syncthreads();

    // ---- hw2 phase: support2 = h1 @ w2 -> B2T rows 0..39 ----
    {
        const int m = t >> 3, n0 = t & 7;
        float a5[5] = {};
        for (int k = 0; k < HD; ++k) {
            const float hv = bf2f(h1s[m][k]);
            #pragma unroll
            for (int j = 0; j < 5; ++j) a5[j] += hv * w2s[k * CD + n0 + 8 * j];
        }
        #pragma unroll
        for (int j = 0; j < 5; ++j) otp[n0 + 8 * j][m] = a5[j];
    }
    __syncthreads();
    for (int i = t; i < CD * 32; i += 256) {
        const int n = i >> 5, mm = i & 31;
        B2T[(size_t)n * NN + mb + mm] = f2bf(otp[n][mm]);
    }
}

// ---------------- K6: finD — sum 8 partials (80-wide), *sinv2, +b2, log_softmax both, store ----------------
__global__ __launch_bounds__(256) void k_finD(const float* __restrict__ U,   // [8][NN][80]
                                              const float* __restrict__ sinv2,
                                              const float* __restrict__ b2,
                                              float* __restrict__ out) {
    __shared__ float vt[32][84];
    const int t = threadIdx.x;
    const int mb = blockIdx.x * 32;
    for (int i = t; i < 32 * 20; i += 256) {
        const int r = i / 20, f4 = i % 20;
        const int m = mb + r;
        f32x4 s = {};
        #pragma unroll
        for (int p = 0; p < 8; ++p) {
            f32x4 v = *(const f32x4*)&U[((size_t)p * NN + m) * 80 + f4 * 4];
            #pragma unroll
            for (int e = 0; e < 4; ++e) s[e] += v[e];
        }
        const float si = sinv2[m];
        #pragma unroll
        for (int e = 0; e < 4; ++e) {
            const int c = f4 * 4 + e;
            float v = s[e] * si;
            if (c < CD) v += b2[c];
            vt[r][c] = v;
        }
    }
    __syncthreads();
    const int l8 = t & 7;
    #pragma unroll
    for (int pass = 0; pass < 2; ++pass) {
        const int task = pass * 32 + (t >> 3);
        const int row = task & 31, mat = task >> 5;
        float vals[5];
        float mx = -3.0e38f;
        #pragma unroll
        for (int j = 0; j < 5; ++j) { vals[j] = vt[row][mat * CD + l8 + 8 * j]; mx = fmaxf(mx, vals[j]); }
        mx = fmaxf(mx, __shfl_xor(mx, 4, 8));
        mx = fmaxf(mx, __shfl_xor(mx, 2, 8));
        mx = fmaxf(mx, __shfl_xor(mx, 1, 8));
        float se = 0.f;
        #pragma unroll
        for (int j = 0; j < 5; ++j) se += expf(vals[j] - mx);
        se += __shfl_xor(se, 4, 8);
        se += __shfl_xor(se, 2, 8);
        se += __shfl_xor(se, 1, 8);
        const float ls = logf(se);
        float* op = out + (size_t)mat * (NN * CD) + (size_t)(mb + row) * CD;
        #pragma unroll
        for (int j = 0; j < 5; ++j) op[l8 + 8 * j] = vals[j] - mx - ls;
    }
}

extern "C" void kernel_launch(void* const* d_in, const int* in_sizes, int n_in,
                              void* d_out, int out_size, void* d_ws, size_t ws_size,
                              hipStream_t stream) {
    (void)in_sizes; (void)n_in; (void)out_size;
    const float* x     = (const float*)d_in[0];
    const float* adj   = (const float*)d_in[1];
    const float* y     = (const float*)d_in[2];
    const float* mask1 = (const float*)d_in[3];
    const float* mask2 = (const float*)d_in[4];
    const float* w1    = (const float*)d_in[5];
    const float* b1    = (const float*)d_in[6];
    const float* w2    = (const float*)d_in[7];
    const float* b2    = (const float*)d_in[8];
    float* out = (float*)d_out;

    const bool both = ws_size >= 313065472ULL;   // P1+P2 resident simultaneously
    char* p = (char*)d_ws;
    unsigned short* P1 = (unsigned short*)p; p += 134217728;
    unsigned short* P2 = P1;
    if (both) { P2 = (unsigned short*)p; p += 134217728; }
    unsigned short* B1T  = (unsigned short*)p; p += 5242880;    // 320x8192 bf16
    unsigned short* B2T  = (unsigned short*)p; p += 1572864;    // 96x8192 bf16 (80 rows used)
    float*          U    = (float*)p;          p += 20971520;   // overlay: Uc[2][8192][320] / Ud[8][8192][80]
    float*          sinv1 = (float*)p;         p += 32768;
    float*          sinv2 = (float*)p;         p += 32768;

    if (both) {
        hipLaunchKernelGGL(k_prep_xw1, dim3(8832), dim3(256), 0, stream,
                           adj, mask1, mask2, P1, P2, sinv1, sinv2, x, w1, y, B1T);
    } else {
        hipLaunchKernelGGL(k_prep_xw1, dim3(8832), dim3(256), 0, stream,
                           adj, mask1, (const float*)nullptr, P1, (unsigned short*)nullptr,
                           sinv1, (float*)nullptr, x, w1, y, B1T);
    }
    hipLaunchKernelGGL(HIP_KERNEL_NAME(k_gemm<64, 2, 2, 2, 5>), dim3(640), dim3(256), 0, stream,
                       P1, B1T, U);
    hipLaunchKernelGGL(k_finC2,   dim3(256),  dim3(256), 0, stream, U, sinv1, b1, w2, B2T);
    if (!both) {
        hipLaunchKernelGGL(k_prep, dim3(8192), dim3(256), 0, stream,
                           adj, mask2, (const float*)nullptr, P1, (unsigned short*)nullptr,
                           sinv2, (float*)nullptr);
    }
    hipLaunchKernelGGL(HIP_KERNEL_NAME(k_gemm<80, 4, 1, 8, 1>), dim3(512), dim3(256), 0, stream,
                       P2, B2T, U);
    hipLaunchKernelGGL(k_finD,    dim3(256),  dim3(256), 0, stream, U, sinv2, b2, out);
}